// Round 1
// baseline (1922.875 us; speedup 1.0000x reference)
//
#include <hip/hip_runtime.h>
#include <hip/hip_bf16.h>

// Problem constants
#define BROWS 16384
#define NDIM  2048
#define NCLS  100

// ---------------------------------------------------------------------------
// GEMM1: C[b][n] = sum_k X[b][k] * W[n][k] + bias[n]
//   X: [16384,2048] row-major, W: [2048,2048] row-major (both K-contiguous: NT gemm)
// Tile: BM=128, BN=128, BK=16; 256 threads; 8x8 microtile per thread.
// ---------------------------------------------------------------------------
__global__ __launch_bounds__(256) void gemm1_kernel(const float* __restrict__ X,
                                                    const float* __restrict__ W,
                                                    const float* __restrict__ bias,
                                                    float* __restrict__ C)
{
    const int K = NDIM;
    __shared__ float sA[16][128];   // [k][m]
    __shared__ float sB[16][128];   // [k][n]

    const int tid = threadIdx.x;
    const int tx = tid & 15;        // n-direction
    const int ty = tid >> 4;        // m-direction
    const int m0 = blockIdx.y * 128;
    const int n0 = blockIdx.x * 128;

    float acc[8][8];
#pragma unroll
    for (int i = 0; i < 8; i++)
#pragma unroll
        for (int j = 0; j < 8; j++) acc[i][j] = 0.0f;

    // staging: each thread loads 8 floats of A and 8 of B (2 float4 each)
    const int s_m = tid >> 1;            // 0..127
    const int s_c = (tid & 1) * 8;       // k offset 0 or 8
    const float* Ag = X + (size_t)(m0 + s_m) * K + s_c;
    const float* Bg = W + (size_t)(n0 + s_m) * K + s_c;

    for (int kt = 0; kt < K; kt += 16) {
        float4 av0 = *(const float4*)(Ag + kt);
        float4 av1 = *(const float4*)(Ag + kt + 4);
        float4 bv0 = *(const float4*)(Bg + kt);
        float4 bv1 = *(const float4*)(Bg + kt + 4);
        __syncthreads();   // previous tile fully consumed
        sA[s_c + 0][s_m] = av0.x; sA[s_c + 1][s_m] = av0.y;
        sA[s_c + 2][s_m] = av0.z; sA[s_c + 3][s_m] = av0.w;
        sA[s_c + 4][s_m] = av1.x; sA[s_c + 5][s_m] = av1.y;
        sA[s_c + 6][s_m] = av1.z; sA[s_c + 7][s_m] = av1.w;
        sB[s_c + 0][s_m] = bv0.x; sB[s_c + 1][s_m] = bv0.y;
        sB[s_c + 2][s_m] = bv0.z; sB[s_c + 3][s_m] = bv0.w;
        sB[s_c + 4][s_m] = bv1.x; sB[s_c + 5][s_m] = bv1.y;
        sB[s_c + 6][s_m] = bv1.z; sB[s_c + 7][s_m] = bv1.w;
        __syncthreads();

#pragma unroll
        for (int k = 0; k < 16; k++) {
            float4 a0 = *(const float4*)&sA[k][ty * 8];
            float4 a1 = *(const float4*)&sA[k][ty * 8 + 4];
            float4 b0 = *(const float4*)&sB[k][tx * 8];
            float4 b1 = *(const float4*)&sB[k][tx * 8 + 4];
            float a[8] = {a0.x, a0.y, a0.z, a0.w, a1.x, a1.y, a1.z, a1.w};
            float b[8] = {b0.x, b0.y, b0.z, b0.w, b1.x, b1.y, b1.z, b1.w};
#pragma unroll
            for (int i = 0; i < 8; i++)
#pragma unroll
                for (int j = 0; j < 8; j++)
                    acc[i][j] = fmaf(a[i], b[j], acc[i][j]);
        }
    }

    // epilogue: add bias, store
    float bb[8];
#pragma unroll
    for (int j = 0; j < 8; j++) bb[j] = bias[n0 + tx * 8 + j];
#pragma unroll
    for (int i = 0; i < 8; i++) {
        const int m = m0 + ty * 8 + i;
        float* crow = C + (size_t)m * NDIM + n0 + tx * 8;
        float4 o0 = make_float4(acc[i][0] + bb[0], acc[i][1] + bb[1],
                                acc[i][2] + bb[2], acc[i][3] + bb[3]);
        float4 o1 = make_float4(acc[i][4] + bb[4], acc[i][5] + bb[5],
                                acc[i][6] + bb[6], acc[i][7] + bb[7]);
        *(float4*)(crow)     = o0;
        *(float4*)(crow + 4) = o1;
    }
}

// ---------------------------------------------------------------------------
// Warp kernel: per row r:
//   gamma = cumsum(softmax(logits_row)) ; warped[k] = interp(gamma[k], linspace(0,1,N), x_row)
// One block (256 threads) per row; 8 elements per thread; in-place on logits buffer.
// ---------------------------------------------------------------------------
__global__ __launch_bounds__(256) void warp_kernel(const float* __restrict__ X,
                                                   float* __restrict__ L)
{
    const int N = NDIM;
    const int row = blockIdx.x;
    const int tid = threadIdx.x;
    const int lane = tid & 63;
    const int wave = tid >> 6;

    __shared__ float s_x[NDIM];
    __shared__ float s_red[4];
    __shared__ float s_wsum[4];

    float* lrow = L + (size_t)row * N;
    const float* xrow = X + (size_t)row * N;

    float v[8];
    {
        float4 l0 = *(const float4*)(lrow + tid * 8);
        float4 l1 = *(const float4*)(lrow + tid * 8 + 4);
        v[0] = l0.x; v[1] = l0.y; v[2] = l0.z; v[3] = l0.w;
        v[4] = l1.x; v[5] = l1.y; v[6] = l1.z; v[7] = l1.w;
        float4 x0 = *(const float4*)(xrow + tid * 8);
        float4 x1 = *(const float4*)(xrow + tid * 8 + 4);
        *(float4*)&s_x[tid * 8]     = x0;
        *(float4*)&s_x[tid * 8 + 4] = x1;
    }

    // block max
    float mx = v[0];
#pragma unroll
    for (int j = 1; j < 8; j++) mx = fmaxf(mx, v[j]);
#pragma unroll
    for (int off = 32; off > 0; off >>= 1) mx = fmaxf(mx, __shfl_down(mx, off));
    if (lane == 0) s_red[wave] = mx;
    __syncthreads();
    mx = fmaxf(fmaxf(s_red[0], s_red[1]), fmaxf(s_red[2], s_red[3]));

    // exp + local inclusive cumsum
    float c = 0.0f;
#pragma unroll
    for (int j = 0; j < 8; j++) {
        float e = __expf(v[j] - mx);
        c += e;
        v[j] = c;              // local inclusive prefix
    }

    // wave-level inclusive scan of per-thread sums
    float sc = c;
#pragma unroll
    for (int off = 1; off < 64; off <<= 1) {
        float t = __shfl_up(sc, off);
        if (lane >= off) sc += t;
    }
    if (lane == 63) s_wsum[wave] = sc;
    __syncthreads();
    float base = 0.0f, total = 0.0f;
#pragma unroll
    for (int w = 0; w < 4; w++) {
        float t = s_wsum[w];
        if (w < wave) base += t;
        total += t;
    }
    const float inv = 1.0f / total;
    const float prefix = base + (sc - c);   // exclusive prefix for this thread

    // interp: pos = gamma*(N-1); gather from s_x
    float w8[8];
#pragma unroll
    for (int j = 0; j < 8; j++) {
        float g = (prefix + v[j]) * inv;
        float pos = g * (float)(N - 1);
        pos = fminf(fmaxf(pos, 0.0f), (float)(N - 1));
        int i = (int)pos;
        if (i > N - 2) i = N - 2;
        float f = pos - (float)i;
        w8[j] = fmaf(f, s_x[i + 1] - s_x[i], s_x[i]);
    }

    float4 o0 = make_float4(w8[0], w8[1], w8[2], w8[3]);
    float4 o1 = make_float4(w8[4], w8[5], w8[6], w8[7]);
    *(float4*)(lrow + tid * 8)     = o0;
    *(float4*)(lrow + tid * 8 + 4) = o1;
}

// ---------------------------------------------------------------------------
// GEMM2: out[b][n] = sum_k Wp[b][k] * F[n][k] + fb[n]   (n < 100)
// Tile: BM=64, BN=128 (100 valid), BK=16; 256 threads; 4x8 microtile.
// ---------------------------------------------------------------------------
__global__ __launch_bounds__(256) void gemm2_kernel(const float* __restrict__ Wp,
                                                    const float* __restrict__ F,
                                                    const float* __restrict__ fb,
                                                    float* __restrict__ out)
{
    const int K = NDIM;
    __shared__ float sA[16][64];
    __shared__ float sB[16][128];

    const int tid = threadIdx.x;
    const int tx = tid & 15;
    const int ty = tid >> 4;
    const int m0 = blockIdx.x * 64;

    float acc[4][8];
#pragma unroll
    for (int i = 0; i < 4; i++)
#pragma unroll
        for (int j = 0; j < 8; j++) acc[i][j] = 0.0f;

    const int a_m = tid >> 2;            // 0..63
    const int a_c = (tid & 3) * 4;       // k offset 0,4,8,12
    const int b_n = tid >> 1;            // 0..127
    const int b_c = (tid & 1) * 8;       // k offset 0 or 8
    const bool bvalid = (b_n < NCLS);
    const float* Ag = Wp + (size_t)(m0 + a_m) * K + a_c;
    const float* Bg = F + (size_t)b_n * K + b_c;

    for (int kt = 0; kt < K; kt += 16) {
        float4 av = *(const float4*)(Ag + kt);
        float4 bv0 = make_float4(0.f, 0.f, 0.f, 0.f);
        float4 bv1 = make_float4(0.f, 0.f, 0.f, 0.f);
        if (bvalid) {
            bv0 = *(const float4*)(Bg + kt);
            bv1 = *(const float4*)(Bg + kt + 4);
        }
        __syncthreads();
        sA[a_c + 0][a_m] = av.x; sA[a_c + 1][a_m] = av.y;
        sA[a_c + 2][a_m] = av.z; sA[a_c + 3][a_m] = av.w;
        sB[b_c + 0][b_n] = bv0.x; sB[b_c + 1][b_n] = bv0.y;
        sB[b_c + 2][b_n] = bv0.z; sB[b_c + 3][b_n] = bv0.w;
        sB[b_c + 4][b_n] = bv1.x; sB[b_c + 5][b_n] = bv1.y;
        sB[b_c + 6][b_n] = bv1.z; sB[b_c + 7][b_n] = bv1.w;
        __syncthreads();

#pragma unroll
        for (int k = 0; k < 16; k++) {
            float4 a4 = *(const float4*)&sA[k][ty * 4];
            float4 b0 = *(const float4*)&sB[k][tx * 8];
            float4 b1 = *(const float4*)&sB[k][tx * 8 + 4];
            float a[4] = {a4.x, a4.y, a4.z, a4.w};
            float b[8] = {b0.x, b0.y, b0.z, b0.w, b1.x, b1.y, b1.z, b1.w};
#pragma unroll
            for (int i = 0; i < 4; i++)
#pragma unroll
                for (int j = 0; j < 8; j++)
                    acc[i][j] = fmaf(a[i], b[j], acc[i][j]);
        }
    }

#pragma unroll
    for (int i = 0; i < 4; i++) {
        const int m = m0 + ty * 4 + i;
#pragma unroll
        for (int j = 0; j < 8; j++) {
            const int n = tx * 8 + j;
            if (n < NCLS) out[(size_t)m * NCLS + n] = acc[i][j] + fb[n];
        }
    }
}

extern "C" void kernel_launch(void* const* d_in, const int* in_sizes, int n_in,
                              void* d_out, int out_size, void* d_ws, size_t ws_size,
                              hipStream_t stream) {
    const float* x  = (const float*)d_in[0];   // time_series [16384,2048]
    const float* ww = (const float*)d_in[1];   // w_weight [2048,2048]
    const float* wb = (const float*)d_in[2];   // w_bias [2048]
    const float* fw = (const float*)d_in[3];   // fc_weight [100,2048]
    const float* fb = (const float*)d_in[4];   // fc_bias [100]
    float* out = (float*)d_out;                // [16384,100]
    float* logits = (float*)d_ws;              // [16384,2048] scratch (128 MiB), reused in-place for warped

    gemm1_kernel<<<dim3(NDIM / 128, BROWS / 128), 256, 0, stream>>>(x, ww, wb, logits);
    warp_kernel<<<BROWS, 256, 0, stream>>>(x, logits);
    gemm2_kernel<<<BROWS / 64, 256, 0, stream>>>(logits, fw, fb, out);
}

// Round 2
// 1023.516 us; speedup vs baseline: 1.8787x; 1.8787x over previous
//
#include <hip/hip_runtime.h>
#include <hip/hip_bf16.h>

// Problem constants
#define BROWS 16384
#define NDIM  2048
#define NCLS  100

typedef __attribute__((ext_vector_type(8))) __bf16 bf16x8;
typedef __attribute__((ext_vector_type(4))) float f32x4;
typedef __attribute__((ext_vector_type(4))) unsigned short u16x4;

__device__ __forceinline__ unsigned short f2bf(float f) {
    union { float f; unsigned int u; } v; v.f = f;
    unsigned int u = v.u;
    unsigned int r = (u + 0x7fffu + ((u >> 16) & 1u)) >> 16;   // RNE
    return (unsigned short)r;
}
__device__ __forceinline__ float bf2f(unsigned short h) {
    union { unsigned int u; float f; } v; v.u = ((unsigned int)h) << 16;
    return v.f;
}

// ---------------------------------------------------------------------------
// split: fp32 -> (hi, lo) bf16 pair. hi = RNE(v), lo = RNE(v - hi).
// ---------------------------------------------------------------------------
__global__ __launch_bounds__(256) void split_kernel(const float4* __restrict__ src,
                                                    u16x4* __restrict__ hi,
                                                    u16x4* __restrict__ lo, int n4)
{
    int i = blockIdx.x * 256 + threadIdx.x;
    if (i >= n4) return;
    float4 v = src[i];
    u16x4 h, l;
    h.x = f2bf(v.x); l.x = f2bf(v.x - bf2f(h.x));
    h.y = f2bf(v.y); l.y = f2bf(v.y - bf2f(h.y));
    h.z = f2bf(v.z); l.z = f2bf(v.z - bf2f(h.z));
    h.w = f2bf(v.w); l.w = f2bf(v.w - bf2f(h.w));
    hi[i] = h; lo[i] = l;
}

// ---------------------------------------------------------------------------
// GEMM1 (MFMA, split-bf16): C[m][n] = sum_k X[m][k]*W[n][k] + bias[n]
//   = Xhi.Whi + Xhi.Wlo + Xlo.Whi  (3 bf16 MFMA passes, fp32 accumulate)
// 128x128 tile, BK=32, 256 threads (4 waves, 2x2), 16x16x32 MFMA, 4x4 per wave.
// global_load_lds width-16 staging; XOR chunk-swizzle (q ^= (r>>1)&3) so the
// ds_read_b128 fragment reads are 2-way (free) instead of 8-way conflicted.
// ---------------------------------------------------------------------------
#define GLOAD_LDS(g, l) \
    __builtin_amdgcn_global_load_lds((const __attribute__((address_space(1))) void*)(g), \
                                     (__attribute__((address_space(3))) void*)(l), 16, 0, 0)

__global__ __launch_bounds__(256) void gemm1_mfma_kernel(const unsigned short* __restrict__ xhi,
                                                         const unsigned short* __restrict__ xlo,
                                                         const unsigned short* __restrict__ whi,
                                                         const unsigned short* __restrict__ wlo,
                                                         const float* __restrict__ bias,
                                                         float* __restrict__ C)
{
    __shared__ unsigned short sA[128 * 32];   // 8 KB, swizzled [r][q^((r>>1)&3)] 16B chunks
    __shared__ unsigned short sB[128 * 32];   // 8 KB

    const int tid  = threadIdx.x;
    const int lane = tid & 63;
    const int w    = tid >> 6;        // wave 0..3
    const int wm   = w & 1;           // wave M half
    const int wn   = w >> 1;          // wave N half
    const int m0   = blockIdx.y * 128;
    const int n0   = blockIdx.x * 128;

    // staging chunk geometry: chunk = 16B = 8 bf16; tile = 512 chunks (128 rows x 4)
    const int c0 = w * 128 + lane;          // t=0 chunk index
    const int r0 = c0 >> 2;
    const int q0 = (c0 & 3) ^ ((r0 >> 1) & 3);
    const int c1 = c0 + 64;                 // t=1 chunk index
    const int r1 = c1 >> 2;
    const int q1 = (c1 & 3) ^ ((r1 >> 1) & 3);

    const size_t a_goff0 = (size_t)(m0 + r0) * NDIM + q0 * 8;
    const size_t a_goff1 = (size_t)(m0 + r1) * NDIM + q1 * 8;
    const size_t b_goff0 = (size_t)(n0 + r0) * NDIM + q0 * 8;
    const size_t b_goff1 = (size_t)(n0 + r1) * NDIM + q1 * 8;

    unsigned short* ldsA0 = &sA[w * 1024];          // wave-uniform LDS bases
    unsigned short* ldsA1 = &sA[w * 1024 + 512];
    unsigned short* ldsB0 = &sB[w * 1024];
    unsigned short* ldsB1 = &sB[w * 1024 + 512];

    // fragment read offsets (element units), swizzle-aware; fixed across K-loop
    const int lm = lane & 15;
    const int lk = lane >> 4;
    int offA[4], offB[4];
#pragma unroll
    for (int i = 0; i < 4; i++) {
        int ra = wm * 64 + i * 16 + lm;
        offA[i] = ra * 32 + ((lk ^ ((ra >> 1) & 3)) * 8);
        int rb = wn * 64 + i * 16 + lm;
        offB[i] = rb * 32 + ((lk ^ ((rb >> 1) & 3)) * 8);
    }

    f32x4 acc[4][4];
#pragma unroll
    for (int i = 0; i < 4; i++)
#pragma unroll
        for (int j = 0; j < 4; j++) acc[i][j] = (f32x4){0.f, 0.f, 0.f, 0.f};

    const unsigned short* pA[3] = {xhi, xhi, xlo};
    const unsigned short* pB[3] = {whi, wlo, whi};

    for (int p = 0; p < 3; ++p) {
        const unsigned short* Ap = pA[p];
        const unsigned short* Bp = pB[p];
        for (int kt = 0; kt < NDIM; kt += 32) {
            GLOAD_LDS(Ap + a_goff0 + kt, ldsA0);
            GLOAD_LDS(Ap + a_goff1 + kt, ldsA1);
            GLOAD_LDS(Bp + b_goff0 + kt, ldsB0);
            GLOAD_LDS(Bp + b_goff1 + kt, ldsB1);
            __syncthreads();   // drains vmcnt(0): tile visible to all waves

            bf16x8 af[4], bf[4];
#pragma unroll
            for (int i = 0; i < 4; i++) af[i] = *(const bf16x8*)&sA[offA[i]];
#pragma unroll
            for (int j = 0; j < 4; j++) bf[j] = *(const bf16x8*)&sB[offB[j]];
#pragma unroll
            for (int i = 0; i < 4; i++)
#pragma unroll
                for (int j = 0; j < 4; j++)
                    acc[i][j] = __builtin_amdgcn_mfma_f32_16x16x32_bf16(af[i], bf[j], acc[i][j], 0, 0, 0);
            __syncthreads();   // all waves done reading before next overwrite
        }
    }

    // epilogue: C/D layout col = lane&15, row = (lane>>4)*4 + reg  [m89-verified]
    const int cn = lane & 15;
    const int rg = lane >> 4;
    float bb[4];
#pragma unroll
    for (int j = 0; j < 4; j++) bb[j] = bias[n0 + wn * 64 + j * 16 + cn];
#pragma unroll
    for (int i = 0; i < 4; i++) {
#pragma unroll
        for (int j = 0; j < 4; j++) {
            const int n = n0 + wn * 64 + j * 16 + cn;
#pragma unroll
            for (int reg = 0; reg < 4; reg++) {
                const int m = m0 + wm * 64 + i * 16 + rg * 4 + reg;
                C[(size_t)m * NDIM + n] = acc[i][j][reg] + bb[j];
            }
        }
    }
}

// ---------------------------------------------------------------------------
// GEMM1 fp32 fallback (proven in R1) — used only if ws_size is too small.
// ---------------------------------------------------------------------------
__global__ __launch_bounds__(256) void gemm1_kernel(const float* __restrict__ X,
                                                    const float* __restrict__ W,
                                                    const float* __restrict__ bias,
                                                    float* __restrict__ C)
{
    const int K = NDIM;
    __shared__ float sA[16][128];
    __shared__ float sB[16][128];

    const int tid = threadIdx.x;
    const int tx = tid & 15;
    const int ty = tid >> 4;
    const int m0 = blockIdx.y * 128;
    const int n0 = blockIdx.x * 128;

    float acc[8][8];
#pragma unroll
    for (int i = 0; i < 8; i++)
#pragma unroll
        for (int j = 0; j < 8; j++) acc[i][j] = 0.0f;

    const int s_m = tid >> 1;
    const int s_c = (tid & 1) * 8;
    const float* Ag = X + (size_t)(m0 + s_m) * K + s_c;
    const float* Bg = W + (size_t)(n0 + s_m) * K + s_c;

    for (int kt = 0; kt < K; kt += 16) {
        float4 av0 = *(const float4*)(Ag + kt);
        float4 av1 = *(const float4*)(Ag + kt + 4);
        float4 bv0 = *(const float4*)(Bg + kt);
        float4 bv1 = *(const float4*)(Bg + kt + 4);
        __syncthreads();
        sA[s_c + 0][s_m] = av0.x; sA[s_c + 1][s_m] = av0.y;
        sA[s_c + 2][s_m] = av0.z; sA[s_c + 3][s_m] = av0.w;
        sA[s_c + 4][s_m] = av1.x; sA[s_c + 5][s_m] = av1.y;
        sA[s_c + 6][s_m] = av1.z; sA[s_c + 7][s_m] = av1.w;
        sB[s_c + 0][s_m] = bv0.x; sB[s_c + 1][s_m] = bv0.y;
        sB[s_c + 2][s_m] = bv0.z; sB[s_c + 3][s_m] = bv0.w;
        sB[s_c + 4][s_m] = bv1.x; sB[s_c + 5][s_m] = bv1.y;
        sB[s_c + 6][s_m] = bv1.z; sB[s_c + 7][s_m] = bv1.w;
        __syncthreads();

#pragma unroll
        for (int k = 0; k < 16; k++) {
            float4 a0 = *(const float4*)&sA[k][ty * 8];
            float4 a1 = *(const float4*)&sA[k][ty * 8 + 4];
            float4 b0 = *(const float4*)&sB[k][tx * 8];
            float4 b1 = *(const float4*)&sB[k][tx * 8 + 4];
            float a[8] = {a0.x, a0.y, a0.z, a0.w, a1.x, a1.y, a1.z, a1.w};
            float b[8] = {b0.x, b0.y, b0.z, b0.w, b1.x, b1.y, b1.z, b1.w};
#pragma unroll
            for (int i = 0; i < 8; i++)
#pragma unroll
                for (int j = 0; j < 8; j++)
                    acc[i][j] = fmaf(a[i], b[j], acc[i][j]);
        }
    }

    float bb[8];
#pragma unroll
    for (int j = 0; j < 8; j++) bb[j] = bias[n0 + tx * 8 + j];
#pragma unroll
    for (int i = 0; i < 8; i++) {
        const int m = m0 + ty * 8 + i;
        float* crow = C + (size_t)m * NDIM + n0 + tx * 8;
        *(float4*)(crow)     = make_float4(acc[i][0] + bb[0], acc[i][1] + bb[1],
                                           acc[i][2] + bb[2], acc[i][3] + bb[3]);
        *(float4*)(crow + 4) = make_float4(acc[i][4] + bb[4], acc[i][5] + bb[5],
                                           acc[i][6] + bb[6], acc[i][7] + bb[7]);
    }
}

// ---------------------------------------------------------------------------
// Warp kernel: gamma = cumsum(softmax(row)); warped = interp(gamma, xs, x_row)
// ---------------------------------------------------------------------------
__global__ __launch_bounds__(256) void warp_kernel(const float* __restrict__ X,
                                                   float* __restrict__ L)
{
    const int N = NDIM;
    const int row = blockIdx.x;
    const int tid = threadIdx.x;
    const int lane = tid & 63;
    const int wave = tid >> 6;

    __shared__ float s_x[NDIM];
    __shared__ float s_red[4];
    __shared__ float s_wsum[4];

    float* lrow = L + (size_t)row * N;
    const float* xrow = X + (size_t)row * N;

    float v[8];
    {
        float4 l0 = *(const float4*)(lrow + tid * 8);
        float4 l1 = *(const float4*)(lrow + tid * 8 + 4);
        v[0] = l0.x; v[1] = l0.y; v[2] = l0.z; v[3] = l0.w;
        v[4] = l1.x; v[5] = l1.y; v[6] = l1.z; v[7] = l1.w;
        float4 x0 = *(const float4*)(xrow + tid * 8);
        float4 x1 = *(const float4*)(xrow + tid * 8 + 4);
        *(float4*)&s_x[tid * 8]     = x0;
        *(float4*)&s_x[tid * 8 + 4] = x1;
    }

    float mx = v[0];
#pragma unroll
    for (int j = 1; j < 8; j++) mx = fmaxf(mx, v[j]);
#pragma unroll
    for (int off = 32; off > 0; off >>= 1) mx = fmaxf(mx, __shfl_down(mx, off));
    if (lane == 0) s_red[wave] = mx;
    __syncthreads();
    mx = fmaxf(fmaxf(s_red[0], s_red[1]), fmaxf(s_red[2], s_red[3]));

    float c = 0.0f;
#pragma unroll
    for (int j = 0; j < 8; j++) {
        float e = __expf(v[j] - mx);
        c += e;
        v[j] = c;
    }

    float sc = c;
#pragma unroll
    for (int off = 1; off < 64; off <<= 1) {
        float t = __shfl_up(sc, off);
        if (lane >= off) sc += t;
    }
    if (lane == 63) s_wsum[wave] = sc;
    __syncthreads();
    float base = 0.0f, total = 0.0f;
#pragma unroll
    for (int w = 0; w < 4; w++) {
        float t = s_wsum[w];
        if (w < wave) base += t;
        total += t;
    }
    const float inv = 1.0f / total;
    const float prefix = base + (sc - c);

    float w8[8];
#pragma unroll
    for (int j = 0; j < 8; j++) {
        float g = (prefix + v[j]) * inv;
        float pos = g * (float)(N - 1);
        pos = fminf(fmaxf(pos, 0.0f), (float)(N - 1));
        int i = (int)pos;
        if (i > N - 2) i = N - 2;
        float f = pos - (float)i;
        w8[j] = fmaf(f, s_x[i + 1] - s_x[i], s_x[i]);
    }

    *(float4*)(lrow + tid * 8)     = make_float4(w8[0], w8[1], w8[2], w8[3]);
    *(float4*)(lrow + tid * 8 + 4) = make_float4(w8[4], w8[5], w8[6], w8[7]);
}

// ---------------------------------------------------------------------------
// GEMM2: out[b][n] = sum_k Wp[b][k] * F[n][k] + fb[n]   (n < 100)
// ---------------------------------------------------------------------------
__global__ __launch_bounds__(256) void gemm2_kernel(const float* __restrict__ Wp,
                                                    const float* __restrict__ F,
                                                    const float* __restrict__ fb,
                                                    float* __restrict__ out)
{
    const int K = NDIM;
    __shared__ float sA[16][64];
    __shared__ float sB[16][128];

    const int tid = threadIdx.x;
    const int tx = tid & 15;
    const int ty = tid >> 4;
    const int m0 = blockIdx.x * 64;

    float acc[4][8];
#pragma unroll
    for (int i = 0; i < 4; i++)
#pragma unroll
        for (int j = 0; j < 8; j++) acc[i][j] = 0.0f;

    const int a_m = tid >> 2;
    const int a_c = (tid & 3) * 4;
    const int b_n = tid >> 1;
    const int b_c = (tid & 1) * 8;
    const bool bvalid = (b_n < NCLS);
    const float* Ag = Wp + (size_t)(m0 + a_m) * K + a_c;
    const float* Bg = F + (size_t)b_n * K + b_c;

    for (int kt = 0; kt < K; kt += 16) {
        float4 av = *(const float4*)(Ag + kt);
        float4 bv0 = make_float4(0.f, 0.f, 0.f, 0.f);
        float4 bv1 = make_float4(0.f, 0.f, 0.f, 0.f);
        if (bvalid) {
            bv0 = *(const float4*)(Bg + kt);
            bv1 = *(const float4*)(Bg + kt + 4);
        }
        __syncthreads();
        sA[a_c + 0][a_m] = av.x; sA[a_c + 1][a_m] = av.y;
        sA[a_c + 2][a_m] = av.z; sA[a_c + 3][a_m] = av.w;
        sB[b_c + 0][b_n] = bv0.x; sB[b_c + 1][b_n] = bv0.y;
        sB[b_c + 2][b_n] = bv0.z; sB[b_c + 3][b_n] = bv0.w;
        sB[b_c + 4][b_n] = bv1.x; sB[b_c + 5][b_n] = bv1.y;
        sB[b_c + 6][b_n] = bv1.z; sB[b_c + 7][b_n] = bv1.w;
        __syncthreads();

#pragma unroll
        for (int k = 0; k < 16; k++) {
            float4 a4 = *(const float4*)&sA[k][ty * 4];
            float4 b0 = *(const float4*)&sB[k][tx * 8];
            float4 b1 = *(const float4*)&sB[k][tx * 8 + 4];
            float a[4] = {a4.x, a4.y, a4.z, a4.w};
            float b[8] = {b0.x, b0.y, b0.z, b0.w, b1.x, b1.y, b1.z, b1.w};
#pragma unroll
            for (int i = 0; i < 4; i++)
#pragma unroll
                for (int j = 0; j < 8; j++)
                    acc[i][j] = fmaf(a[i], b[j], acc[i][j]);
        }
    }

#pragma unroll
    for (int i = 0; i < 4; i++) {
        const int m = m0 + ty * 4 + i;
#pragma unroll
        for (int j = 0; j < 8; j++) {
            const int n = tx * 8 + j;
            if (n < NCLS) out[(size_t)m * NCLS + n] = acc[i][j] + fb[n];
        }
    }
}

extern "C" void kernel_launch(void* const* d_in, const int* in_sizes, int n_in,
                              void* d_out, int out_size, void* d_ws, size_t ws_size,
                              hipStream_t stream) {
    const float* x  = (const float*)d_in[0];   // time_series [16384,2048]
    const float* ww = (const float*)d_in[1];   // w_weight [2048,2048]
    const float* wb = (const float*)d_in[2];   // w_bias [2048]
    const float* fw = (const float*)d_in[3];   // fc_weight [100,2048]
    const float* fb = (const float*)d_in[4];   // fc_bias [100]
    float* out = (float*)d_out;                // [16384,100]

    char* ws = (char*)d_ws;
    float* logits = (float*)ws;                                   // 128 MiB fp32
    const size_t LOGITS_B = (size_t)BROWS * NDIM * 4;             // 134217728
    const size_t XBF_B    = (size_t)BROWS * NDIM * 2;             // 67108864
    const size_t WBF_B    = (size_t)NDIM * NDIM * 2;              // 8388608
    unsigned short* xhi = (unsigned short*)(ws + LOGITS_B);
    unsigned short* xlo = (unsigned short*)(ws + LOGITS_B + XBF_B);
    unsigned short* whi = (unsigned short*)(ws + LOGITS_B + 2 * XBF_B);
    unsigned short* wlo = (unsigned short*)(ws + LOGITS_B + 2 * XBF_B + WBF_B);
    const size_t WS_NEED = LOGITS_B + 2 * XBF_B + 2 * WBF_B;      // 285212672

    if (ws_size >= WS_NEED) {
        split_kernel<<<(BROWS * NDIM / 4 + 255) / 256, 256, 0, stream>>>(
            (const float4*)x, (u16x4*)xhi, (u16x4*)xlo, BROWS * NDIM / 4);
        split_kernel<<<(NDIM * NDIM / 4 + 255) / 256, 256, 0, stream>>>(
            (const float4*)ww, (u16x4*)whi, (u16x4*)wlo, NDIM * NDIM / 4);
        gemm1_mfma_kernel<<<dim3(NDIM / 128, BROWS / 128), 256, 0, stream>>>(
            xhi, xlo, whi, wlo, wb, logits);
    } else {
        gemm1_kernel<<<dim3(NDIM / 128, BROWS / 128), 256, 0, stream>>>(x, ww, wb, logits);
    }
    warp_kernel<<<BROWS, 256, 0, stream>>>(x, logits);
    gemm2_kernel<<<BROWS / 64, 256, 0, stream>>>(logits, fw, fb, out);
}

// Round 3
// 699.237 us; speedup vs baseline: 2.7500x; 1.4638x over previous
//
#include <hip/hip_runtime.h>
#include <hip/hip_bf16.h>

// Problem constants
#define BROWS 16384
#define NDIM  2048
#define NCLS  100

typedef __attribute__((ext_vector_type(8))) __bf16 bf16x8;
typedef __attribute__((ext_vector_type(4))) float f32x4;
typedef __attribute__((ext_vector_type(4))) unsigned short u16x4;
typedef __attribute__((ext_vector_type(8))) unsigned short u16x8;

__device__ __forceinline__ unsigned short f2bf(float f) {
    union { float f; unsigned int u; } v; v.f = f;
    unsigned int u = v.u;
    unsigned int r = (u + 0x7fffu + ((u >> 16) & 1u)) >> 16;   // RNE
    return (unsigned short)r;
}
__device__ __forceinline__ float bf2f(unsigned short h) {
    union { unsigned int u; float f; } v; v.u = ((unsigned int)h) << 16;
    return v.f;
}

#define GLOAD_LDS(g, l) \
    __builtin_amdgcn_global_load_lds((const __attribute__((address_space(1))) void*)(g), \
                                     (__attribute__((address_space(3))) void*)(l), 16, 0, 0)

// ---------------------------------------------------------------------------
// split: fp32 -> (hi, lo) bf16 pair. hi = RNE(v), lo = RNE(v - hi).
// ---------------------------------------------------------------------------
__global__ __launch_bounds__(256) void split_kernel(const float4* __restrict__ src,
                                                    u16x4* __restrict__ hi,
                                                    u16x4* __restrict__ lo, int n4)
{
    int i = blockIdx.x * 256 + threadIdx.x;
    if (i >= n4) return;
    float4 v = src[i];
    u16x4 h, l;
    h.x = f2bf(v.x); l.x = f2bf(v.x - bf2f(h.x));
    h.y = f2bf(v.y); l.y = f2bf(v.y - bf2f(h.y));
    h.z = f2bf(v.z); l.z = f2bf(v.z - bf2f(h.z));
    h.w = f2bf(v.w); l.w = f2bf(v.w - bf2f(h.w));
    hi[i] = h; lo[i] = l;
}

// fp32 -> bf16 (hi only), for fc_weight
__global__ __launch_bounds__(256) void cvt_bf16_kernel(const float4* __restrict__ src,
                                                       u16x4* __restrict__ dst, int n4)
{
    int i = blockIdx.x * 256 + threadIdx.x;
    if (i >= n4) return;
    float4 v = src[i];
    u16x4 h;
    h.x = f2bf(v.x); h.y = f2bf(v.y); h.z = f2bf(v.z); h.w = f2bf(v.w);
    dst[i] = h;
}

// ---------------------------------------------------------------------------
// GEMM1 (MFMA, split-bf16, FUSED): C = Xhi.Whi + Xhi.Wlo + Xlo.Whi + bias
// Single K-loop: stage Ahi/Alo/Bhi/Blo tiles once per kt, 48 MFMA per
// barrier-pair (3x the amortization of the 3-pass version; 33% less fetch).
// 128x128 tile, BK=32, 256 threads (4 waves 2x2), 16x16x32 MFMA, 4x4/wave.
// XOR chunk-swizzle (q ^= (r>>1)&3): ds_read_b128 frags 2-way = free.
// ---------------------------------------------------------------------------
__global__ __launch_bounds__(256) void gemm1_mfma_fused_kernel(
        const unsigned short* __restrict__ xhi,
        const unsigned short* __restrict__ xlo,
        const unsigned short* __restrict__ whi,
        const unsigned short* __restrict__ wlo,
        const float* __restrict__ bias,
        float* __restrict__ C)
{
    __shared__ unsigned short sAh[128 * 32];   // 8 KB each
    __shared__ unsigned short sAl[128 * 32];
    __shared__ unsigned short sBh[128 * 32];
    __shared__ unsigned short sBl[128 * 32];

    const int tid  = threadIdx.x;
    const int lane = tid & 63;
    const int w    = tid >> 6;
    const int wm   = w & 1;
    const int wn   = w >> 1;
    const int m0   = blockIdx.y * 128;
    const int n0   = blockIdx.x * 128;

    // staging chunk geometry: chunk = 16B = 8 bf16; tile = 512 chunks (128r x 4)
    const int c0 = w * 128 + lane;
    const int r0 = c0 >> 2;
    const int q0 = (c0 & 3) ^ ((r0 >> 1) & 3);
    const int c1 = c0 + 64;
    const int r1 = c1 >> 2;
    const int q1 = (c1 & 3) ^ ((r1 >> 1) & 3);

    const size_t a_goff0 = (size_t)(m0 + r0) * NDIM + q0 * 8;
    const size_t a_goff1 = (size_t)(m0 + r1) * NDIM + q1 * 8;
    const size_t b_goff0 = (size_t)(n0 + r0) * NDIM + q0 * 8;
    const size_t b_goff1 = (size_t)(n0 + r1) * NDIM + q1 * 8;

    unsigned short* ldsAh0 = &sAh[w * 1024];   unsigned short* ldsAh1 = &sAh[w * 1024 + 512];
    unsigned short* ldsAl0 = &sAl[w * 1024];   unsigned short* ldsAl1 = &sAl[w * 1024 + 512];
    unsigned short* ldsBh0 = &sBh[w * 1024];   unsigned short* ldsBh1 = &sBh[w * 1024 + 512];
    unsigned short* ldsBl0 = &sBl[w * 1024];   unsigned short* ldsBl1 = &sBl[w * 1024 + 512];

    const int lm = lane & 15;
    const int lk = lane >> 4;
    int offA[4], offB[4];
#pragma unroll
    for (int i = 0; i < 4; i++) {
        int ra = wm * 64 + i * 16 + lm;
        offA[i] = ra * 32 + ((lk ^ ((ra >> 1) & 3)) * 8);
        int rb = wn * 64 + i * 16 + lm;
        offB[i] = rb * 32 + ((lk ^ ((rb >> 1) & 3)) * 8);
    }

    f32x4 acc[4][4];
#pragma unroll
    for (int i = 0; i < 4; i++)
#pragma unroll
        for (int j = 0; j < 4; j++) acc[i][j] = (f32x4){0.f, 0.f, 0.f, 0.f};

    for (int kt = 0; kt < NDIM; kt += 32) {
        GLOAD_LDS(xhi + a_goff0 + kt, ldsAh0);
        GLOAD_LDS(xhi + a_goff1 + kt, ldsAh1);
        GLOAD_LDS(xlo + a_goff0 + kt, ldsAl0);
        GLOAD_LDS(xlo + a_goff1 + kt, ldsAl1);
        GLOAD_LDS(whi + b_goff0 + kt, ldsBh0);
        GLOAD_LDS(whi + b_goff1 + kt, ldsBh1);
        GLOAD_LDS(wlo + b_goff0 + kt, ldsBl0);
        GLOAD_LDS(wlo + b_goff1 + kt, ldsBl1);
        __syncthreads();

        bf16x8 ah[4], al[4], bh[4], bl[4];
#pragma unroll
        for (int i = 0; i < 4; i++) {
            ah[i] = *(const bf16x8*)&sAh[offA[i]];
            al[i] = *(const bf16x8*)&sAl[offA[i]];
            bh[i] = *(const bf16x8*)&sBh[offB[i]];
            bl[i] = *(const bf16x8*)&sBl[offB[i]];
        }
#pragma unroll
        for (int i = 0; i < 4; i++)
#pragma unroll
            for (int j = 0; j < 4; j++) {
                acc[i][j] = __builtin_amdgcn_mfma_f32_16x16x32_bf16(ah[i], bh[j], acc[i][j], 0, 0, 0);
                acc[i][j] = __builtin_amdgcn_mfma_f32_16x16x32_bf16(ah[i], bl[j], acc[i][j], 0, 0, 0);
                acc[i][j] = __builtin_amdgcn_mfma_f32_16x16x32_bf16(al[i], bh[j], acc[i][j], 0, 0, 0);
            }
        __syncthreads();
    }

    // epilogue: C/D layout col = lane&15, row = (lane>>4)*4 + reg
    const int cn = lane & 15;
    const int rg = lane >> 4;
    float bb[4];
#pragma unroll
    for (int j = 0; j < 4; j++) bb[j] = bias[n0 + wn * 64 + j * 16 + cn];
#pragma unroll
    for (int i = 0; i < 4; i++) {
#pragma unroll
        for (int j = 0; j < 4; j++) {
            const int n = n0 + wn * 64 + j * 16 + cn;
#pragma unroll
            for (int reg = 0; reg < 4; reg++) {
                const int m = m0 + wm * 64 + i * 16 + rg * 4 + reg;
                C[(size_t)m * NDIM + n] = acc[i][j][reg] + bb[j];
            }
        }
    }
}

// ---------------------------------------------------------------------------
// Warp kernel: gamma = cumsum(softmax(row)); warped = interp(gamma, xs, x_row)
// Writes warped as bf16 (for the MFMA GEMM2).
// ---------------------------------------------------------------------------
__global__ __launch_bounds__(256) void warp_bf16_kernel(const float* __restrict__ X,
                                                        const float* __restrict__ L,
                                                        unsigned short* __restrict__ Wout)
{
    const int N = NDIM;
    const int row = blockIdx.x;
    const int tid = threadIdx.x;
    const int lane = tid & 63;
    const int wave = tid >> 6;

    __shared__ float s_x[NDIM];
    __shared__ float s_red[4];
    __shared__ float s_wsum[4];

    const float* lrow = L + (size_t)row * N;
    const float* xrow = X + (size_t)row * N;

    float v[8];
    {
        float4 l0 = *(const float4*)(lrow + tid * 8);
        float4 l1 = *(const float4*)(lrow + tid * 8 + 4);
        v[0] = l0.x; v[1] = l0.y; v[2] = l0.z; v[3] = l0.w;
        v[4] = l1.x; v[5] = l1.y; v[6] = l1.z; v[7] = l1.w;
        float4 x0 = *(const float4*)(xrow + tid * 8);
        float4 x1 = *(const float4*)(xrow + tid * 8 + 4);
        *(float4*)&s_x[tid * 8]     = x0;
        *(float4*)&s_x[tid * 8 + 4] = x1;
    }

    float mx = v[0];
#pragma unroll
    for (int j = 1; j < 8; j++) mx = fmaxf(mx, v[j]);
#pragma unroll
    for (int off = 32; off > 0; off >>= 1) mx = fmaxf(mx, __shfl_down(mx, off));
    if (lane == 0) s_red[wave] = mx;
    __syncthreads();
    mx = fmaxf(fmaxf(s_red[0], s_red[1]), fmaxf(s_red[2], s_red[3]));

    float c = 0.0f;
#pragma unroll
    for (int j = 0; j < 8; j++) {
        float e = __expf(v[j] - mx);
        c += e;
        v[j] = c;
    }

    float sc = c;
#pragma unroll
    for (int off = 1; off < 64; off <<= 1) {
        float t = __shfl_up(sc, off);
        if (lane >= off) sc += t;
    }
    if (lane == 63) s_wsum[wave] = sc;
    __syncthreads();
    float base = 0.0f, total = 0.0f;
#pragma unroll
    for (int w = 0; w < 4; w++) {
        float t = s_wsum[w];
        if (w < wave) base += t;
        total += t;
    }
    const float inv = 1.0f / total;
    const float prefix = base + (sc - c);

    u16x8 o;
#pragma unroll
    for (int j = 0; j < 8; j++) {
        float g = (prefix + v[j]) * inv;
        float pos = g * (float)(N - 1);
        pos = fminf(fmaxf(pos, 0.0f), (float)(N - 1));
        int i = (int)pos;
        if (i > N - 2) i = N - 2;
        float f = pos - (float)i;
        o[j] = f2bf(fmaf(f, s_x[i + 1] - s_x[i], s_x[i]));
    }
    *(u16x8*)(Wout + (size_t)row * N + tid * 8) = o;
}

// ---------------------------------------------------------------------------
// GEMM2 (MFMA bf16): out[m][n] = sum_k Wp[m][k] * F[n][k] + fb[n]  (n<100)
// BM=64, BN=128 (rows>=100 clamped, masked at store), BK=32, 4 waves 2x2
// each 32x64 (2x4 frags). 256 blocks.
// ---------------------------------------------------------------------------
__global__ __launch_bounds__(256) void gemm2_mfma_kernel(
        const unsigned short* __restrict__ Wp,   // warped bf16 [16384][2048]
        const unsigned short* __restrict__ F,    // fc bf16 [100][2048]
        const float* __restrict__ fb,
        float* __restrict__ out)
{
    __shared__ unsigned short sA[64 * 32];    // 4 KB
    __shared__ unsigned short sB[128 * 32];   // 8 KB

    const int tid  = threadIdx.x;
    const int lane = tid & 63;
    const int w    = tid >> 6;
    const int wm   = w & 1;    // 2 m-halves of 32
    const int wn   = w >> 1;   // 2 n-halves of 64
    const int m0   = blockIdx.x * 64;

    // A staging: 256 chunks, 1/thread
    const int ca = w * 64 + lane;
    const int ra = ca >> 2;
    const int qa = (ca & 3) ^ ((ra >> 1) & 3);
    const size_t a_goff = (size_t)(m0 + ra) * NDIM + qa * 8;
    unsigned short* ldsA = &sA[w * 512];

    // B staging: 512 chunks, 2/thread; source row clamped to 99
    const int cb0 = w * 128 + lane;
    const int rb0 = cb0 >> 2;
    const int qb0 = (cb0 & 3) ^ ((rb0 >> 1) & 3);
    const int cb1 = cb0 + 64;
    const int rb1 = cb1 >> 2;
    const int qb1 = (cb1 & 3) ^ ((rb1 >> 1) & 3);
    const size_t b_goff0 = (size_t)(rb0 < NCLS ? rb0 : NCLS - 1) * NDIM + qb0 * 8;
    const size_t b_goff1 = (size_t)(rb1 < NCLS ? rb1 : NCLS - 1) * NDIM + qb1 * 8;
    unsigned short* ldsB0 = &sB[w * 1024];
    unsigned short* ldsB1 = &sB[w * 1024 + 512];

    const int lm = lane & 15;
    const int lk = lane >> 4;
    int offA[2], offB[4];
#pragma unroll
    for (int i = 0; i < 2; i++) {
        int r = wm * 32 + i * 16 + lm;
        offA[i] = r * 32 + ((lk ^ ((r >> 1) & 3)) * 8);
    }
#pragma unroll
    for (int j = 0; j < 4; j++) {
        int r = wn * 64 + j * 16 + lm;
        offB[j] = r * 32 + ((lk ^ ((r >> 1) & 3)) * 8);
    }

    f32x4 acc[2][4];
#pragma unroll
    for (int i = 0; i < 2; i++)
#pragma unroll
        for (int j = 0; j < 4; j++) acc[i][j] = (f32x4){0.f, 0.f, 0.f, 0.f};

    for (int kt = 0; kt < NDIM; kt += 32) {
        GLOAD_LDS(Wp + a_goff + kt, ldsA);
        GLOAD_LDS(F + b_goff0 + kt, ldsB0);
        GLOAD_LDS(F + b_goff1 + kt, ldsB1);
        __syncthreads();

        bf16x8 af[2], bf[4];
#pragma unroll
        for (int i = 0; i < 2; i++) af[i] = *(const bf16x8*)&sA[offA[i]];
#pragma unroll
        for (int j = 0; j < 4; j++) bf[j] = *(const bf16x8*)&sB[offB[j]];
#pragma unroll
        for (int i = 0; i < 2; i++)
#pragma unroll
            for (int j = 0; j < 4; j++)
                acc[i][j] = __builtin_amdgcn_mfma_f32_16x16x32_bf16(af[i], bf[j], acc[i][j], 0, 0, 0);
        __syncthreads();
    }

    const int cn = lane & 15;
    const int rg = lane >> 4;
#pragma unroll
    for (int i = 0; i < 2; i++) {
#pragma unroll
        for (int j = 0; j < 4; j++) {
            const int n = wn * 64 + j * 16 + cn;
            if (n < NCLS) {
                const float bbn = fb[n];
#pragma unroll
                for (int reg = 0; reg < 4; reg++) {
                    const int m = m0 + wm * 32 + i * 16 + rg * 4 + reg;
                    out[(size_t)m * NCLS + n] = acc[i][j][reg] + bbn;
                }
            }
        }
    }
}

// ---------------------------------------------------------------------------
// fp32 fallback path (only if ws_size too small) — proven R1 kernels.
// ---------------------------------------------------------------------------
__global__ __launch_bounds__(256) void gemm1_kernel(const float* __restrict__ X,
                                                    const float* __restrict__ W,
                                                    const float* __restrict__ bias,
                                                    float* __restrict__ C)
{
    const int K = NDIM;
    __shared__ float sA[16][128];
    __shared__ float sB[16][128];
    const int tid = threadIdx.x;
    const int tx = tid & 15;
    const int ty = tid >> 4;
    const int m0 = blockIdx.y * 128;
    const int n0 = blockIdx.x * 128;
    float acc[8][8];
#pragma unroll
    for (int i = 0; i < 8; i++)
#pragma unroll
        for (int j = 0; j < 8; j++) acc[i][j] = 0.0f;
    const int s_m = tid >> 1;
    const int s_c = (tid & 1) * 8;
    const float* Ag = X + (size_t)(m0 + s_m) * K + s_c;
    const float* Bg = W + (size_t)(n0 + s_m) * K + s_c;
    for (int kt = 0; kt < K; kt += 16) {
        float4 av0 = *(const float4*)(Ag + kt);
        float4 av1 = *(const float4*)(Ag + kt + 4);
        float4 bv0 = *(const float4*)(Bg + kt);
        float4 bv1 = *(const float4*)(Bg + kt + 4);
        __syncthreads();
        sA[s_c + 0][s_m] = av0.x; sA[s_c + 1][s_m] = av0.y;
        sA[s_c + 2][s_m] = av0.z; sA[s_c + 3][s_m] = av0.w;
        sA[s_c + 4][s_m] = av1.x; sA[s_c + 5][s_m] = av1.y;
        sA[s_c + 6][s_m] = av1.z; sA[s_c + 7][s_m] = av1.w;
        sB[s_c + 0][s_m] = bv0.x; sB[s_c + 1][s_m] = bv0.y;
        sB[s_c + 2][s_m] = bv0.z; sB[s_c + 3][s_m] = bv0.w;
        sB[s_c + 4][s_m] = bv1.x; sB[s_c + 5][s_m] = bv1.y;
        sB[s_c + 6][s_m] = bv1.z; sB[s_c + 7][s_m] = bv1.w;
        __syncthreads();
#pragma unroll
        for (int k = 0; k < 16; k++) {
            float4 a0 = *(const float4*)&sA[k][ty * 8];
            float4 a1 = *(const float4*)&sA[k][ty * 8 + 4];
            float4 b0 = *(const float4*)&sB[k][tx * 8];
            float4 b1 = *(const float4*)&sB[k][tx * 8 + 4];
            float a[8] = {a0.x, a0.y, a0.z, a0.w, a1.x, a1.y, a1.z, a1.w};
            float b[8] = {b0.x, b0.y, b0.z, b0.w, b1.x, b1.y, b1.z, b1.w};
#pragma unroll
            for (int i = 0; i < 8; i++)
#pragma unroll
                for (int j = 0; j < 8; j++)
                    acc[i][j] = fmaf(a[i], b[j], acc[i][j]);
        }
    }
    float bb[8];
#pragma unroll
    for (int j = 0; j < 8; j++) bb[j] = bias[n0 + tx * 8 + j];
#pragma unroll
    for (int i = 0; i < 8; i++) {
        const int m = m0 + ty * 8 + i;
        float* crow = C + (size_t)m * NDIM + n0 + tx * 8;
        *(float4*)(crow)     = make_float4(acc[i][0] + bb[0], acc[i][1] + bb[1],
                                           acc[i][2] + bb[2], acc[i][3] + bb[3]);
        *(float4*)(crow + 4) = make_float4(acc[i][4] + bb[4], acc[i][5] + bb[5],
                                           acc[i][6] + bb[6], acc[i][7] + bb[7]);
    }
}

__global__ __launch_bounds__(256) void warp_kernel_f32(const float* __restrict__ X,
                                                       float* __restrict__ L)
{
    const int N = NDIM;
    const int row = blockIdx.x;
    const int tid = threadIdx.x;
    const int lane = tid & 63;
    const int wave = tid >> 6;
    __shared__ float s_x[NDIM];
    __shared__ float s_red[4];
    __shared__ float s_wsum[4];
    float* lrow = L + (size_t)row * N;
    const float* xrow = X + (size_t)row * N;
    float v[8];
    {
        float4 l0 = *(const float4*)(lrow + tid * 8);
        float4 l1 = *(const float4*)(lrow + tid * 8 + 4);
        v[0] = l0.x; v[1] = l0.y; v[2] = l0.z; v[3] = l0.w;
        v[4] = l1.x; v[5] = l1.y; v[6] = l1.z; v[7] = l1.w;
        float4 x0 = *(const float4*)(xrow + tid * 8);
        float4 x1 = *(const float4*)(xrow + tid * 8 + 4);
        *(float4*)&s_x[tid * 8]     = x0;
        *(float4*)&s_x[tid * 8 + 4] = x1;
    }
    float mx = v[0];
#pragma unroll
    for (int j = 1; j < 8; j++) mx = fmaxf(mx, v[j]);
#pragma unroll
    for (int off = 32; off > 0; off >>= 1) mx = fmaxf(mx, __shfl_down(mx, off));
    if (lane == 0) s_red[wave] = mx;
    __syncthreads();
    mx = fmaxf(fmaxf(s_red[0], s_red[1]), fmaxf(s_red[2], s_red[3]));
    float c = 0.0f;
#pragma unroll
    for (int j = 0; j < 8; j++) {
        float e = __expf(v[j] - mx);
        c += e;
        v[j] = c;
    }
    float sc = c;
#pragma unroll
    for (int off = 1; off < 64; off <<= 1) {
        float t = __shfl_up(sc, off);
        if (lane >= off) sc += t;
    }
    if (lane == 63) s_wsum[wave] = sc;
    __syncthreads();
    float base = 0.0f, total = 0.0f;
#pragma unroll
    for (int w = 0; w < 4; w++) {
        float t = s_wsum[w];
        if (w < wave) base += t;
        total += t;
    }
    const float inv = 1.0f / total;
    const float prefix = base + (sc - c);
    float w8[8];
#pragma unroll
    for (int j = 0; j < 8; j++) {
        float g = (prefix + v[j]) * inv;
        float pos = g * (float)(N - 1);
        pos = fminf(fmaxf(pos, 0.0f), (float)(N - 1));
        int i = (int)pos;
        if (i > N - 2) i = N - 2;
        float f = pos - (float)i;
        w8[j] = fmaf(f, s_x[i + 1] - s_x[i], s_x[i]);
    }
    *(float4*)(lrow + tid * 8)     = make_float4(w8[0], w8[1], w8[2], w8[3]);
    *(float4*)(lrow + tid * 8 + 4) = make_float4(w8[4], w8[5], w8[6], w8[7]);
}

__global__ __launch_bounds__(256) void gemm2_kernel(const float* __restrict__ Wp,
                                                    const float* __restrict__ F,
                                                    const float* __restrict__ fb,
                                                    float* __restrict__ out)
{
    const int K = NDIM;
    __shared__ float sA[16][64];
    __shared__ float sB[16][128];
    const int tid = threadIdx.x;
    const int tx = tid & 15;
    const int ty = tid >> 4;
    const int m0 = blockIdx.x * 64;
    float acc[4][8];
#pragma unroll
    for (int i = 0; i < 4; i++)
#pragma unroll
        for (int j = 0; j < 8; j++) acc[i][j] = 0.0f;
    const int a_m = tid >> 2;
    const int a_c = (tid & 3) * 4;
    const int b_n = tid >> 1;
    const int b_c = (tid & 1) * 8;
    const bool bvalid = (b_n < NCLS);
    const float* Ag = Wp + (size_t)(m0 + a_m) * K + a_c;
    const float* Bg = F + (size_t)b_n * K + b_c;
    for (int kt = 0; kt < K; kt += 16) {
        float4 av = *(const float4*)(Ag + kt);
        float4 bv0 = make_float4(0.f, 0.f, 0.f, 0.f);
        float4 bv1 = make_float4(0.f, 0.f, 0.f, 0.f);
        if (bvalid) {
            bv0 = *(const float4*)(Bg + kt);
            bv1 = *(const float4*)(Bg + kt + 4);
        }
        __syncthreads();
        sA[a_c + 0][a_m] = av.x; sA[a_c + 1][a_m] = av.y;
        sA[a_c + 2][a_m] = av.z; sA[a_c + 3][a_m] = av.w;
        sB[b_c + 0][b_n] = bv0.x; sB[b_c + 1][b_n] = bv0.y;
        sB[b_c + 2][b_n] = bv0.z; sB[b_c + 3][b_n] = bv0.w;
        sB[b_c + 4][b_n] = bv1.x; sB[b_c + 5][b_n] = bv1.y;
        sB[b_c + 6][b_n] = bv1.z; sB[b_c + 7][b_n] = bv1.w;
        __syncthreads();
#pragma unroll
        for (int k = 0; k < 16; k++) {
            float4 a4 = *(const float4*)&sA[k][ty * 4];
            float4 b0 = *(const float4*)&sB[k][tx * 8];
            float4 b1 = *(const float4*)&sB[k][tx * 8 + 4];
            float a[4] = {a4.x, a4.y, a4.z, a4.w};
            float b[8] = {b0.x, b0.y, b0.z, b0.w, b1.x, b1.y, b1.z, b1.w};
#pragma unroll
            for (int i = 0; i < 4; i++)
#pragma unroll
                for (int j = 0; j < 8; j++)
                    acc[i][j] = fmaf(a[i], b[j], acc[i][j]);
        }
    }
#pragma unroll
    for (int i = 0; i < 4; i++) {
        const int m = m0 + ty * 4 + i;
#pragma unroll
        for (int j = 0; j < 8; j++) {
            const int n = tx * 8 + j;
            if (n < NCLS) out[(size_t)m * NCLS + n] = acc[i][j] + fb[n];
        }
    }
}

extern "C" void kernel_launch(void* const* d_in, const int* in_sizes, int n_in,
                              void* d_out, int out_size, void* d_ws, size_t ws_size,
                              hipStream_t stream) {
    const float* x  = (const float*)d_in[0];   // time_series [16384,2048]
    const float* ww = (const float*)d_in[1];   // w_weight [2048,2048]
    const float* wb = (const float*)d_in[2];   // w_bias [2048]
    const float* fw = (const float*)d_in[3];   // fc_weight [100,2048]
    const float* fb = (const float*)d_in[4];   // fc_bias [100]
    float* out = (float*)d_out;                // [16384,100]

    char* ws = (char*)d_ws;
    float* logits = (float*)ws;                                   // 128 MiB fp32
    const size_t LOGITS_B = (size_t)BROWS * NDIM * 4;             // 134217728
    const size_t XBF_B    = (size_t)BROWS * NDIM * 2;             // 67108864
    const size_t WBF_B    = (size_t)NDIM * NDIM * 2;              // 8388608
    unsigned short* xhi = (unsigned short*)(ws + LOGITS_B);
    unsigned short* xlo = (unsigned short*)(ws + LOGITS_B + XBF_B);
    unsigned short* whi = (unsigned short*)(ws + LOGITS_B + 2 * XBF_B);
    unsigned short* wlo = (unsigned short*)(ws + LOGITS_B + 2 * XBF_B + WBF_B);
    // aliases (dead after gemm1): warped bf16 reuses xlo; fc bf16 reuses wlo
    unsigned short* wbf = xlo;
    unsigned short* fwb = wlo;
    const size_t WS_NEED = LOGITS_B + 2 * XBF_B + 2 * WBF_B;      // 285212672 (same as R2)

    if (ws_size >= WS_NEED) {
        split_kernel<<<(BROWS * NDIM / 4 + 255) / 256, 256, 0, stream>>>(
            (const float4*)x, (u16x4*)xhi, (u16x4*)xlo, BROWS * NDIM / 4);
        split_kernel<<<(NDIM * NDIM / 4 + 255) / 256, 256, 0, stream>>>(
            (const float4*)ww, (u16x4*)whi, (u16x4*)wlo, NDIM * NDIM / 4);
        gemm1_mfma_fused_kernel<<<dim3(NDIM / 128, BROWS / 128), 256, 0, stream>>>(
            xhi, xlo, whi, wlo, wb, logits);
        warp_bf16_kernel<<<BROWS, 256, 0, stream>>>(x, logits, wbf);
        cvt_bf16_kernel<<<(NCLS * NDIM / 4 + 255) / 256, 256, 0, stream>>>(
            (const float4*)fw, (u16x4*)fwb, NCLS * NDIM / 4);
        gemm2_mfma_kernel<<<BROWS / 64, 256, 0, stream>>>(wbf, fwb, fb, out);
    } else {
        gemm1_kernel<<<dim3(NDIM / 128, BROWS / 128), 256, 0, stream>>>(x, ww, wb, logits);
        warp_kernel_f32<<<BROWS, 256, 0, stream>>>(x, logits);
        gemm2_kernel<<<BROWS / 64, 256, 0, stream>>>(logits, fw, fb, out);
    }
}